// Round 6
// baseline (3881.735 us; speedup 1.0000x reference)
//
#include <hip/hip_runtime.h>

#define NTOK 32768
#define NE   2048
#define EDIM 128
#define NQ   4

#define TOKT 128         // tokens per block
#define CODT 512         // codes per tile
#define DCH  8           // d-rows per staged chunk
#define NTILE (NE / CODT)        // 4
#define NCHPT (EDIM / DCH)       // 16 chunks per tile
#define NCH   (NTILE * NCHPT)    // 64 total chunks

// ---------------------------------------------------------------------------
__global__ __launch_bounds__(256) void cnorm_init_kernel(
    const float* __restrict__ cb, float* __restrict__ cnorm,
    float* __restrict__ loss_accum)
{
    const int code = blockIdx.x * 256 + threadIdx.x;   // 0 .. NQ*NE-1
    if (code == 0) *loss_accum = 0.0f;
    const float4* row = (const float4*)(cb + (size_t)code * EDIM);
    float s = 0.0f;
#pragma unroll
    for (int j = 0; j < EDIM / 4; ++j) {
        float4 v = row[j];
        s += v.x * v.x; s += v.y * v.y; s += v.z * v.z; s += v.w * v.w;
    }
    cnorm[code] = s;
}

// ---------------------------------------------------------------------------
// codebook transpose: cbT[l][d][c] = cb[l][c][d]
// ---------------------------------------------------------------------------
__global__ __launch_bounds__(256) void transpose_cb_kernel(
    const float* __restrict__ cb, float* __restrict__ cbT)
{
    __shared__ __align__(16) float S[64][129];
    const int t  = threadIdx.x;
    const int l  = blockIdx.x >> 5;
    const int c0 = (blockIdx.x & 31) * 64;
    const float* src = cb + ((size_t)l * NE + c0) * EDIM;
#pragma unroll
    for (int k = 0; k < 8; ++k) {
        const int idx = k * 256 + t;
        const int cc  = idx >> 5;
        const int dq  = idx & 31;
        float4 v = *(const float4*)(src + (size_t)cc * EDIM + dq * 4);
        S[cc][dq * 4 + 0] = v.x; S[cc][dq * 4 + 1] = v.y;
        S[cc][dq * 4 + 2] = v.z; S[cc][dq * 4 + 3] = v.w;
    }
    __syncthreads();
    float* dst = cbT + (size_t)l * EDIM * NE;
#pragma unroll
    for (int k = 0; k < 8; ++k) {
        const int idx = k * 256 + t;
        const int d   = idx >> 4;
        const int cq  = idx & 15;
        float4 w;
        w.x = S[cq * 4 + 0][d]; w.y = S[cq * 4 + 1][d];
        w.z = S[cq * 4 + 2][d]; w.w = S[cq * 4 + 3][d];
        *(float4*)(dst + (size_t)d * NE + c0 + cq * 4) = w;
    }
}

// ---------------------------------------------------------------------------
// register-tile macros: NO stack aggregates anywhere in the hot kernel
// ---------------------------------------------------------------------------
#define F4FMA(C, S, B) { C.x += (S)*(B).x; C.y += (S)*(B).y; \
                         C.z += (S)*(B).z; C.w += (S)*(B).w; }

#define DECL_ROW(i) float4 acc##i##_0, acc##i##_1, acc##i##_2, acc##i##_3;
#define ZERO_ROW(i) { acc##i##_0 = z4; acc##i##_1 = z4; \
                      acc##i##_2 = z4; acc##i##_3 = z4; }
#define FMA_ROW(i, S) { F4FMA(acc##i##_0, S, b0) F4FMA(acc##i##_1, S, b1) \
                        F4FMA(acc##i##_2, S, b2) F4FMA(acc##i##_3, S, b3) }

// thread ty owns codes cb0v + m*128 + j  (m=0..3, j=0..3), cb0v = tile*512+ty*4
#define ACMP(i, AV, CV, J) { const float dd = (rni - 2.0f*(AV)) + (CV); \
    if (dd < bd##i) { bd##i = dd; bi##i = cb0v + (J); } }
#define ARGROW(i) { const float rni = rn##i; \
    ACMP(i, acc##i##_0.x, q0.x, 0)    ACMP(i, acc##i##_0.y, q0.y, 1) \
    ACMP(i, acc##i##_0.z, q0.z, 2)    ACMP(i, acc##i##_0.w, q0.w, 3) \
    ACMP(i, acc##i##_1.x, q1.x, 128)  ACMP(i, acc##i##_1.y, q1.y, 129) \
    ACMP(i, acc##i##_1.z, q1.z, 130)  ACMP(i, acc##i##_1.w, q1.w, 131) \
    ACMP(i, acc##i##_2.x, q2.x, 256)  ACMP(i, acc##i##_2.y, q2.y, 257) \
    ACMP(i, acc##i##_2.z, q2.z, 258)  ACMP(i, acc##i##_2.w, q2.w, 259) \
    ACMP(i, acc##i##_3.x, q3.x, 384)  ACMP(i, acc##i##_3.y, q3.y, 385) \
    ACMP(i, acc##i##_3.z, q3.z, 386)  ACMP(i, acc##i##_3.w, q3.w, 387) }

#define RED(i) { float od = __shfl_xor(bd##i, m, 64); \
                 int   oi = __shfl_xor(bi##i, m, 64); \
    if (od < bd##i || (od == bd##i && oi < bi##i)) { bd##i = od; bi##i = oi; } }

// thread tx's token for acc row i: (i>>1)*32 + tx*2 + (i&1)
#define STB(i, TK) { red_df[w * TOKT + (TK)] = bd##i; \
                     red_if[w * TOKT + (TK)] = bi##i; }

#define RNI(i, TK) const float rn##i = ((part[TK] + part[TOKT + (TK)]) \
                 + part[2 * TOKT + (TK)]) + part[3 * TOKT + (TK)];

__device__ __forceinline__ void gld16(const float* g, const float* l) {
    __builtin_amdgcn_global_load_lds(
        (const __attribute__((address_space(1))) unsigned int*)(const void*)g,
        (__attribute__((address_space(3))) unsigned int*)(void*)(l),
        16, 0, 0);
}

// ---------------------------------------------------------------------------
// One VQ level. 512-thread block (8 waves -> co-residency FORCES 2 waves/SIMD),
// 1 block per CU (96 KB LDS), grid = 256 = #CUs exactly. 8x16 micro-tile in
// named registers; strided code/token ownership makes every LDS read
// conflict-free (B: 4 addrs x 4 banks over 16 banks; A: b64 over all 32).
// waves_per_eu(1): allocator free (round-4-proven no-spill at ~190 VGPR).
// ---------------------------------------------------------------------------
__attribute__((amdgpu_waves_per_eu(1)))
__global__ __launch_bounds__(512) void vq_level_kernel(
    const float* __restrict__ rin,
    const float* __restrict__ cb,      // row-major codebook (gather)
    const float* __restrict__ cbT,     // transposed codebook [EDIM][NE]
    const float* __restrict__ cnorm,
    float* __restrict__ rout,
    float* __restrict__ xq,
    float* __restrict__ idx_out,
    float* __restrict__ loss_accum,
    int level, int first)
{
    __shared__ __align__(16) float A[EDIM][TOKT];       // 64 KB
    __shared__ __align__(16) float Bsh[2][DCH][CODT];   // 32 KB (dbuf)

    float* part   = &Bsh[1][0][0];            // [4][128], pre-loop only
    float* ovl    = &Bsh[0][0][0];            // post-loop overlays (16 KB)
    float* red_df = ovl;                      // [8][128]
    int*   red_if = (int*)(ovl + 1024);       // [8][128]
    int*   idx_s  = (int*)(ovl + 2048);       // [128]
    float* lsum   = ovl + 2304;               // [512]

    const int t    = threadIdx.x;
    const int tok0 = blockIdx.x * TOKT;
    const int tx   = t & 15;                  // token group
    const int ty   = t >> 4;                  // 0..31 code group
    const int tx2  = tx * 2;
    const int ty4  = ty * 4;

    // B staging geometry: thread does 2 gld16; f = k*512 + t (float4 index),
    // row = f>>7 (wave-uniform), col = (f&127)*4 (lane-contiguous).
    const int w    = t >> 6;                  // wave id 0..7
    const int lduni0 = (t & 448) * 4;         // wave-uniform float offset, k=0
    const int gcol0  = (t & 127) * 4;         // k=0 per-lane float col
    // k=1: f = 512+t -> row += 4, col same pattern

    // ---- stage residual tile (transposed) + partial norms ----
    {
        const int tok = t & 127;
        const int dg  = t >> 7;               // 0..3, 32 dims each
        float s = 0.0f;
#pragma unroll
        for (int j = 0; j < 8; ++j) {
            const int d0 = dg * 32 + j * 4;
            float4 v = *(const float4*)(rin + (size_t)(tok0 + tok) * EDIM + d0);
            A[d0 + 0][tok] = v.x; A[d0 + 1][tok] = v.y;
            A[d0 + 2][tok] = v.z; A[d0 + 3][tok] = v.w;
            s += v.x * v.x; s += v.y * v.y; s += v.z * v.z; s += v.w * v.w;
        }
        part[dg * TOKT + tok] = s;
    }
    __syncthreads();   // bar1

    RNI(0, tx2)      RNI(1, tx2 + 1)
    RNI(2, tx2 + 32) RNI(3, tx2 + 33)
    RNI(4, tx2 + 64) RNI(5, tx2 + 65)
    RNI(6, tx2 + 96) RNI(7, tx2 + 97)

    // ---- stage chunk 0 into buf0 (tile 0, dc 0) via global_load_lds ----
    {
        const int row0 = (t & 448) >> 7;      // f>>7 for k=0 (wave-uniform)
        gld16(cbT + (size_t)row0 * NE + gcol0,       &Bsh[0][0][0] + lduni0);
        gld16(cbT + (size_t)(row0 + 4) * NE + gcol0, &Bsh[0][0][0] + lduni0 + 2048);
    }
    __syncthreads();   // bar2: chunk0 resident (barrier drains vmcnt)

    float bd0, bd1, bd2, bd3, bd4, bd5, bd6, bd7;
    int   bi0, bi1, bi2, bi3, bi4, bi5, bi6, bi7;
    bd0 = bd1 = bd2 = bd3 = bd4 = bd5 = bd6 = bd7 = 3.402823466e38f;
    bi0 = bi1 = bi2 = bi3 = bi4 = bi5 = bi6 = bi7 = 0;

    DECL_ROW(0) DECL_ROW(1) DECL_ROW(2) DECL_ROW(3)
    DECL_ROW(4) DECL_ROW(5) DECL_ROW(6) DECL_ROW(7)
    const float4 z4 = make_float4(0.f, 0.f, 0.f, 0.f);

    for (int c = 0; c < NCH; ++c) {
        const int buf  = c & 1;
        const int tile = c >> 4;
        const int dc   = c & 15;

        if (dc == 0) {
            ZERO_ROW(0) ZERO_ROW(1) ZERO_ROW(2) ZERO_ROW(3)
            ZERO_ROW(4) ZERO_ROW(5) ZERO_ROW(6) ZERO_ROW(7)
        }

        // ---- issue next chunk's DMA into buf^1 ----
        const int cnx = c + 1;
        if (cnx < NCH) {
            const int tile_n = cnx >> 4;
            const int dc_n   = cnx & 15;
            const int row0   = (t & 448) >> 7;
            const float* gsrc = cbT + (size_t)(dc_n * DCH + row0) * NE
                                + tile_n * CODT + gcol0;
            float* ld = &Bsh[buf ^ 1][0][0] + lduni0;
            gld16(gsrc,          ld);
            gld16(gsrc + 4 * NE, ld + 2048);
        }

        // ---- compute 8 d-steps from buf ----
        const float* Bb = &Bsh[buf][0][0];
        const int dbase = dc * DCH;
#pragma unroll
        for (int d = 0; d < DCH; ++d) {
            const float* Arow = &A[0][0] + (dbase + d) * TOKT;
            float2 a0 = *(const float2*)(Arow + tx2);
            float2 a1 = *(const float2*)(Arow + 32 + tx2);
            float2 a2 = *(const float2*)(Arow + 64 + tx2);
            float2 a3 = *(const float2*)(Arow + 96 + tx2);
            const float* Brow = Bb + d * CODT + ty4;
            float4 b0 = *(const float4*)(Brow);
            float4 b1 = *(const float4*)(Brow + 128);
            float4 b2 = *(const float4*)(Brow + 256);
            float4 b3 = *(const float4*)(Brow + 384);
            FMA_ROW(0, a0.x) FMA_ROW(1, a0.y)
            FMA_ROW(2, a1.x) FMA_ROW(3, a1.y)
            FMA_ROW(4, a2.x) FMA_ROW(5, a2.y)
            FMA_ROW(6, a3.x) FMA_ROW(7, a3.y)
        }

        // ---- argmin at tile end (registers only) ----
        if (dc == 15) {
            const int cb0v = tile * CODT + ty4;
            const float4 q0 = *(const float4*)(cnorm + cb0v);
            const float4 q1 = *(const float4*)(cnorm + cb0v + 128);
            const float4 q2 = *(const float4*)(cnorm + cb0v + 256);
            const float4 q3 = *(const float4*)(cnorm + cb0v + 384);
            ARGROW(0) ARGROW(1) ARGROW(2) ARGROW(3)
            ARGROW(4) ARGROW(5) ARGROW(6) ARGROW(7)
        }
        __syncthreads();   // buf^1 DMA drained; buf free for overwrite
    }

    // ---- in-wave argmin reduce across the 4 ty values in this wave ----
    for (int m = 16; m < 64; m <<= 1) {
        RED(0) RED(1) RED(2) RED(3) RED(4) RED(5) RED(6) RED(7)
    }
    if ((t & 63) < 16) {                      // one lane per tx per wave
        STB(0, tx2)      STB(1, tx2 + 1)
        STB(2, tx2 + 32) STB(3, tx2 + 33)
        STB(4, tx2 + 64) STB(5, tx2 + 65)
        STB(6, tx2 + 96) STB(7, tx2 + 97)
    }
    __syncthreads();
    if (t < TOKT) {
        float bdv = red_df[t];
        int   biv = red_if[t];
#pragma unroll
        for (int ww = 1; ww < 8; ++ww) {
            const float dd = red_df[ww * TOKT + t];
            const int   ii = red_if[ww * TOKT + t];
            if (dd < bdv || (dd == bdv && ii < biv)) { bdv = dd; biv = ii; }
        }
        idx_s[t] = biv;
        idx_out[(size_t)(tok0 + t) * NQ + level] = (float)biv;
    }
    __syncthreads();

    // ---- epilogue: gather + straight-through update + loss partial ----
    {
        const int tok = t >> 2;      // 0..127
        const int dq  = t & 3;       // 4 threads per token, 32 dims each
        const int gi  = idx_s[tok];
        const float* qrow = cb + (size_t)gi * EDIM;
        float lp = 0.0f;
#pragma unroll
        for (int k = 0; k < 8; ++k) {
            const int d0 = k * 16 + dq * 4;
            const float4 q = *(const float4*)(qrow + d0);
            float4 r;
            r.x = A[d0 + 0][tok]; r.y = A[d0 + 1][tok];
            r.z = A[d0 + 2][tok]; r.w = A[d0 + 3][tok];
            float4 tq, qst, rnv;
            tq.x = q.x - r.x; tq.y = q.y - r.y; tq.z = q.z - r.z; tq.w = q.w - r.w;
            qst.x = r.x + tq.x; qst.y = r.y + tq.y;
            qst.z = r.z + tq.z; qst.w = r.w + tq.w;
            rnv.x = r.x - qst.x; rnv.y = r.y - qst.y;
            rnv.z = r.z - qst.z; rnv.w = r.w - qst.w;
            const size_t go = (size_t)(tok0 + tok) * EDIM + d0;
            *(float4*)(rout + go) = rnv;
            if (first) {
                *(float4*)(xq + go) = qst;
            } else {
                float4 o = *(const float4*)(xq + go);
                o.x += qst.x; o.y += qst.y; o.z += qst.z; o.w += qst.w;
                *(float4*)(xq + go) = o;
            }
            lp += tq.x * tq.x; lp += tq.y * tq.y;
            lp += tq.z * tq.z; lp += tq.w * tq.w;
        }
        lsum[t] = lp;
    }
    __syncthreads();
#pragma unroll
    for (int s2 = 256; s2 > 0; s2 >>= 1) {
        if (t < s2) lsum[t] += lsum[t + s2];
        __syncthreads();
    }
    if (t == 0) atomicAdd(loss_accum, lsum[0]);
}

// ---------------------------------------------------------------------------
__global__ void finalize_kernel(const float* __restrict__ loss_accum,
                                float* __restrict__ out_loss)
{
    *out_loss = *loss_accum * (1.25f / (4.0f * (float)NTOK * (float)EDIM));
}

extern "C" void kernel_launch(void* const* d_in, const int* in_sizes, int n_in,
                              void* d_out, int out_size, void* d_ws, size_t ws_size,
                              hipStream_t stream)
{
    const float* x  = (const float*)d_in[0];
    const float* cb = (const float*)d_in[1];

    float* out      = (float*)d_out;
    float* xq       = out;
    float* out_loss = out + (size_t)NTOK * EDIM;
    float* idx_out  = out + (size_t)NTOK * EDIM + 1;

    float* ws         = (float*)d_ws;
    float* cnorm      = ws;
    float* loss_accum = ws + 8192;
    float* cbT        = ws + 8448;
    float* r0         = cbT + (size_t)NQ * EDIM * NE;

    transpose_cb_kernel<<<NQ * (NE / 64), 256, 0, stream>>>(cb, cbT);
    cnorm_init_kernel<<<(NQ * NE) / 256, 256, 0, stream>>>(cb, cnorm, loss_accum);

    for (int l = 0; l < NQ; ++l) {
        const float* rin = (l == 0) ? x : r0;
        vq_level_kernel<<<NTOK / TOKT, 512, 0, stream>>>(
            rin,
            cb + (size_t)l * NE * EDIM,
            cbT + (size_t)l * EDIM * NE,
            cnorm + (size_t)l * NE,
            r0, xq, idx_out, loss_accum, l, (l == 0) ? 1 : 0);
    }
    finalize_kernel<<<1, 1, 0, stream>>>(loss_accum, out_loss);
}

// Round 8
// 1028.199 us; speedup vs baseline: 3.7753x; 3.7753x over previous
//
#include <hip/hip_runtime.h>

#define NTOK 32768
#define NE   2048
#define EDIM 128
#define NQ   4

#define TOKT 64          // tokens per block
#define CODT 256         // codes per tile
#define DCH  8           // d-rows per staged chunk
#define NTILE (NE / CODT)        // 8 tiles
#define NCHPT (EDIM / DCH)       // 16 chunks per tile
#define NCH   (NTILE * NCHPT)    // 128 total chunks

// ---------------------------------------------------------------------------
__global__ __launch_bounds__(256) void cnorm_init_kernel(
    const float* __restrict__ cb, float* __restrict__ cnorm,
    float* __restrict__ loss_accum)
{
    const int code = blockIdx.x * 256 + threadIdx.x;   // 0 .. NQ*NE-1
    if (code == 0) *loss_accum = 0.0f;
    const float4* row = (const float4*)(cb + (size_t)code * EDIM);
    float s = 0.0f;
#pragma unroll
    for (int j = 0; j < EDIM / 4; ++j) {
        float4 v = row[j];
        s += v.x * v.x; s += v.y * v.y; s += v.z * v.z; s += v.w * v.w;
    }
    cnorm[code] = s;
}

// ---------------------------------------------------------------------------
// codebook transpose: cbT[l][d][c] = cb[l][c][d]
// ---------------------------------------------------------------------------
__global__ __launch_bounds__(256) void transpose_cb_kernel(
    const float* __restrict__ cb, float* __restrict__ cbT)
{
    __shared__ __align__(16) float S[64][129];
    const int t  = threadIdx.x;
    const int l  = blockIdx.x >> 5;
    const int c0 = (blockIdx.x & 31) * 64;
    const float* src = cb + ((size_t)l * NE + c0) * EDIM;
#pragma unroll
    for (int k = 0; k < 8; ++k) {
        const int idx = k * 256 + t;
        const int cc  = idx >> 5;
        const int dq  = idx & 31;
        float4 v = *(const float4*)(src + (size_t)cc * EDIM + dq * 4);
        S[cc][dq * 4 + 0] = v.x; S[cc][dq * 4 + 1] = v.y;
        S[cc][dq * 4 + 2] = v.z; S[cc][dq * 4 + 3] = v.w;
    }
    __syncthreads();
    float* dst = cbT + (size_t)l * EDIM * NE;
#pragma unroll
    for (int k = 0; k < 8; ++k) {
        const int idx = k * 256 + t;
        const int d   = idx >> 4;
        const int cq  = idx & 15;
        float4 w;
        w.x = S[cq * 4 + 0][d]; w.y = S[cq * 4 + 1][d];
        w.z = S[cq * 4 + 2][d]; w.w = S[cq * 4 + 3][d];
        *(float4*)(dst + (size_t)d * NE + c0 + cq * 4) = w;
    }
}

// ---------------------------------------------------------------------------
// register-tile macros: NO stack aggregates anywhere in the hot kernel
// ---------------------------------------------------------------------------
#define F4FMA(C, S, B) { C.x += (S)*(B).x; C.y += (S)*(B).y; \
                         C.z += (S)*(B).z; C.w += (S)*(B).w; }

#define DECL_ROW(i) float4 acc##i##_0, acc##i##_1;
#define ZERO_ROW(i) { acc##i##_0 = z4; acc##i##_1 = z4; }
#define FMA_ROW(i, S) { F4FMA(acc##i##_0, S, b0) F4FMA(acc##i##_1, S, b1) }

#define ACMP(i, AV, CV, J) { const float dd = (rni - 2.0f*(AV)) + (CV); \
    if (dd < bd##i) { bd##i = dd; bi##i = cb0v + (J); } }
#define ARGROW(i) { const float rni = rns[tx8 + i]; \
    ACMP(i, acc##i##_0.x, q0.x, 0)  ACMP(i, acc##i##_0.y, q0.y, 1) \
    ACMP(i, acc##i##_0.z, q0.z, 2)  ACMP(i, acc##i##_0.w, q0.w, 3) \
    ACMP(i, acc##i##_1.x, q1.x, 4)  ACMP(i, acc##i##_1.y, q1.y, 5) \
    ACMP(i, acc##i##_1.z, q1.z, 6)  ACMP(i, acc##i##_1.w, q1.w, 7) }

#define RED(i) { float od = __shfl_xor(bd##i, m, 64); \
                 int   oi = __shfl_xor(bi##i, m, 64); \
    if (od < bd##i || (od == bd##i && oi < bi##i)) { bd##i = od; bi##i = oi; } }

#define STB(i) { red_df[w * 64 + tx8 + i] = bd##i; \
                 red_if[w * 64 + tx8 + i] = bi##i; }

__device__ __forceinline__ void gld16(const float* g, const float* l) {
    __builtin_amdgcn_global_load_lds(
        (const __attribute__((address_space(1))) unsigned int*)(const void*)g,
        (__attribute__((address_space(3))) unsigned int*)(void*)(l),
        16, 0, 0);
}

// ---------------------------------------------------------------------------
// One VQ level. 8x8 register micro-tile trimmed for the 128-VGPR cap:
// rn in LDS (read only at tile ends), DCH=8 (2 gld16/thread/chunk),
// dc-loop unrolled x2 so the LDS buffer index is compile-time.
// FIX vs round 7: chunk linear id is c = tile*NCHPT + dc with NCHPT=16;
// prefetch decode is tile_n = cnx>>4, dc_n = cnx&15 (round 7 used the
// DCH=16-era tile<<3 / >>3 / &7 and staged wrong B data for half the
// chunks -> corrupted argmins).
// ~49.5 KB LDS -> 3 blocks/CU. grid = 512 blocks, 256 threads.
// ---------------------------------------------------------------------------
__global__ __launch_bounds__(256, 2) void vq_level_kernel(
    const float* __restrict__ rin,
    const float* __restrict__ cb,      // row-major codebook (gather)
    const float* __restrict__ cbT,     // transposed codebook [EDIM][NE]
    const float* __restrict__ cnorm,
    float* __restrict__ rout,
    float* __restrict__ xq,
    float* __restrict__ idx_out,
    float* __restrict__ loss_accum,
    int level, int first)
{
    __shared__ __align__(16) float A[EDIM][TOKT];       // 32 KB
    __shared__ __align__(16) float Bsh[2][DCH][CODT];   // 16 KB (dbuf)
    __shared__ float part[4 * 64];                      // 1 KB (pre-loop)
    __shared__ float rns[TOKT];                         // 256 B (persistent)

    // post-loop overlays inside Bsh (compute loop fully done before use)
    float* ovl    = &Bsh[0][0][0];
    float* red_df = ovl;                      // [4][64]
    int*   red_if = (int*)(ovl + 256);        // [4][64]
    int*   idx_s  = (int*)(ovl + 512);        // [64]
    float* lsum   = ovl + 576;                // [256]

    const int t    = threadIdx.x;
    const int tok0 = blockIdx.x * TOKT;
    const int tx   = t & 7;
    const int ty   = t >> 3;                  // 0..31
    const int tx8  = tx * 8;
    const int ty8  = ty * 8;
    const int w    = t >> 6;                  // wave id

    // B staging: 2 gld16/thread; float4 index f = k*256 + t (k=0,1)
    // row = f>>6 (= grow + 4k, wave-uniform), col floats = (f&63)*4
    const int grow = t >> 6;
    const int gcol = (t & 63) * 4;
    const int lduni = (t & 192) * 4;          // wave-uniform float offset

    // ---- stage residual tile (transposed) + partial norms ----
    {
        const int tok = t & 63;
        const int dg  = t >> 6;
        float s = 0.0f;
#pragma unroll
        for (int j = 0; j < 8; ++j) {
            const int d0 = dg * 32 + j * 4;
            float4 v = *(const float4*)(rin + (size_t)(tok0 + tok) * EDIM + d0);
            A[d0 + 0][tok] = v.x; A[d0 + 1][tok] = v.y;
            A[d0 + 2][tok] = v.z; A[d0 + 3][tok] = v.w;
            s += v.x * v.x; s += v.y * v.y; s += v.z * v.z; s += v.w * v.w;
        }
        part[dg * 64 + tok] = s;
    }
    __syncthreads();   // bar1

    // token norms -> rns (same association as reference chain)
    if (t < TOKT)
        rns[t] = ((part[t] + part[64 + t]) + part[128 + t]) + part[192 + t];

    // ---- stage chunk 0 into buf0 (tile 0, dc 0) via global_load_lds ----
    {
        const float* gsrc = cbT + (size_t)grow * NE + gcol;
        float* ld = &Bsh[0][0][0] + lduni;
        gld16(gsrc,          ld);
        gld16(gsrc + 4 * NE, ld + 1024);
    }
    __syncthreads();   // bar2: chunk0 resident + rns visible

    float bd0, bd1, bd2, bd3, bd4, bd5, bd6, bd7;
    int   bi0, bi1, bi2, bi3, bi4, bi5, bi6, bi7;
    bd0 = bd1 = bd2 = bd3 = bd4 = bd5 = bd6 = bd7 = 3.402823466e38f;
    bi0 = bi1 = bi2 = bi3 = bi4 = bi5 = bi6 = bi7 = 0;

    DECL_ROW(0) DECL_ROW(1) DECL_ROW(2) DECL_ROW(3)
    DECL_ROW(4) DECL_ROW(5) DECL_ROW(6) DECL_ROW(7)
    const float4 z4 = make_float4(0.f, 0.f, 0.f, 0.f);

    // one chunk: prefetch c+1 into BUFP, compute dc from BUFC (compile-time BUFs)
#define DOCHUNK(PHASE, BUFC, BUFP)                                          \
    {                                                                       \
        const int dc  = (dc2 << 1) + (PHASE);                               \
        const int cnx = tile * NCHPT + dc + 1;   /* linear id of next */    \
        if (cnx < NCH) {                                                    \
            const int tile_n = cnx >> 4;         /* NCHPT = 16 */           \
            const int dc_n   = cnx & 15;                                    \
            const float* gsrc = cbT + (size_t)(dc_n * DCH + grow) * NE      \
                                + tile_n * CODT + gcol;                     \
            float* ld = &Bsh[BUFP][0][0] + lduni;                           \
            gld16(gsrc,          ld);                                       \
            gld16(gsrc + 4 * NE, ld + 1024);                                \
        }                                                                   \
        const float* Arow0 = &A[0][0] + dc * (DCH * TOKT) + tx8;            \
        _Pragma("unroll")                                                   \
        for (int d = 0; d < DCH; ++d) {                                     \
            float4 a0 = *(const float4*)(Arow0 + d * TOKT);                 \
            float4 a1 = *(const float4*)(Arow0 + d * TOKT + 4);             \
            const float* Brow = &Bsh[BUFC][0][0] + d * CODT + ty8;          \
            float4 b0 = *(const float4*)(Brow);                             \
            float4 b1 = *(const float4*)(Brow + 4);                         \
            FMA_ROW(0, a0.x) FMA_ROW(1, a0.y)                               \
            FMA_ROW(2, a0.z) FMA_ROW(3, a0.w)                               \
            FMA_ROW(4, a1.x) FMA_ROW(5, a1.y)                               \
            FMA_ROW(6, a1.z) FMA_ROW(7, a1.w)                               \
        }                                                                   \
        __syncthreads();                                                    \
    }

    for (int tile = 0; tile < NTILE; ++tile) {
        ZERO_ROW(0) ZERO_ROW(1) ZERO_ROW(2) ZERO_ROW(3)
        ZERO_ROW(4) ZERO_ROW(5) ZERO_ROW(6) ZERO_ROW(7)

        for (int dc2 = 0; dc2 < NCHPT / 2; ++dc2) {
            DOCHUNK(0, 0, 1)
            DOCHUNK(1, 1, 0)
        }

        // ---- argmin over this tile's 8 columns (regs + rns/cnorm reads) ----
        {
            const int cb0v = tile * CODT + ty8;
            const float4 q0 = *(const float4*)(cnorm + cb0v);
            const float4 q1 = *(const float4*)(cnorm + cb0v + 4);
            ARGROW(0) ARGROW(1) ARGROW(2) ARGROW(3)
            ARGROW(4) ARGROW(5) ARGROW(6) ARGROW(7)
        }
    }
#undef DOCHUNK

    // ---- in-wave argmin reduce across ty (lanes sharing tx) ----
    for (int m = 8; m < 64; m <<= 1) {
        RED(0) RED(1) RED(2) RED(3) RED(4) RED(5) RED(6) RED(7)
    }
    if ((t & 63) < 8) {                       // one lane per tx per wave
        STB(0) STB(1) STB(2) STB(3) STB(4) STB(5) STB(6) STB(7)
    }
    __syncthreads();
    if (t < TOKT) {
        float bdv = red_df[t];
        int   biv = red_if[t];
#pragma unroll
        for (int ww = 1; ww < 4; ++ww) {
            const float dd = red_df[ww * 64 + t];
            const int   ii = red_if[ww * 64 + t];
            if (dd < bdv || (dd == bdv && ii < biv)) { bdv = dd; biv = ii; }
        }
        idx_s[t] = biv;
        idx_out[(size_t)(tok0 + t) * NQ + level] = (float)biv;
    }
    __syncthreads();

    // ---- epilogue: gather + straight-through update + loss partial ----
    {
        const int tok = t >> 2;
        const int dq  = t & 3;
        const int gi  = idx_s[tok];
        const float* qrow = cb + (size_t)gi * EDIM;
        float lp = 0.0f;
#pragma unroll
        for (int k = 0; k < 8; ++k) {
            const int d0 = k * 16 + dq * 4;
            const float4 q = *(const float4*)(qrow + d0);
            float4 r;
            r.x = A[d0 + 0][tok]; r.y = A[d0 + 1][tok];
            r.z = A[d0 + 2][tok]; r.w = A[d0 + 3][tok];
            float4 tq, qst, rnv;
            tq.x = q.x - r.x; tq.y = q.y - r.y; tq.z = q.z - r.z; tq.w = q.w - r.w;
            qst.x = r.x + tq.x; qst.y = r.y + tq.y;
            qst.z = r.z + tq.z; qst.w = r.w + tq.w;
            rnv.x = r.x - qst.x; rnv.y = r.y - qst.y;
            rnv.z = r.z - qst.z; rnv.w = r.w - qst.w;
            const size_t go = (size_t)(tok0 + tok) * EDIM + d0;
            *(float4*)(rout + go) = rnv;
            if (first) {
                *(float4*)(xq + go) = qst;
            } else {
                float4 o = *(const float4*)(xq + go);
                o.x += qst.x; o.y += qst.y; o.z += qst.z; o.w += qst.w;
                *(float4*)(xq + go) = o;
            }
            lp += tq.x * tq.x; lp += tq.y * tq.y;
            lp += tq.z * tq.z; lp += tq.w * tq.w;
        }
        lsum[t] = lp;
    }
    __syncthreads();
#pragma unroll
    for (int s2 = 128; s2 > 0; s2 >>= 1) {
        if (t < s2) lsum[t] += lsum[t + s2];
        __syncthreads();
    }
    if (t == 0) atomicAdd(loss_accum, lsum[0]);
}

// ---------------------------------------------------------------------------
__global__ void finalize_kernel(const float* __restrict__ loss_accum,
                                float* __restrict__ out_loss)
{
    *out_loss = *loss_accum * (1.25f / (4.0f * (float)NTOK * (float)EDIM));
}

extern "C" void kernel_launch(void* const* d_in, const int* in_sizes, int n_in,
                              void* d_out, int out_size, void* d_ws, size_t ws_size,
                              hipStream_t stream)
{
    const float* x  = (const float*)d_in[0];
    const float* cb = (const float*)d_in[1];

    float* out      = (float*)d_out;
    float* xq       = out;
    float* out_loss = out + (size_t)NTOK * EDIM;
    float* idx_out  = out + (size_t)NTOK * EDIM + 1;

    float* ws         = (float*)d_ws;
    float* cnorm      = ws;
    float* loss_accum = ws + 8192;
    float* cbT        = ws + 8448;
    float* r0         = cbT + (size_t)NQ * EDIM * NE;

    transpose_cb_kernel<<<NQ * (NE / 64), 256, 0, stream>>>(cb, cbT);
    cnorm_init_kernel<<<(NQ * NE) / 256, 256, 0, stream>>>(cb, cnorm, loss_accum);

    for (int l = 0; l < NQ; ++l) {
        const float* rin = (l == 0) ? x : r0;
        vq_level_kernel<<<NTOK / TOKT, 256, 0, stream>>>(
            rin,
            cb + (size_t)l * NE * EDIM,
            cbT + (size_t)l * EDIM * NE,
            cnorm + (size_t)l * NE,
            r0, xq, idx_out, loss_accum, l, (l == 0) ? 1 : 0);
    }
    finalize_kernel<<<1, 1, 0, stream>>>(loss_accum, out_loss);
}

// Round 9
// 371.863 us; speedup vs baseline: 10.4386x; 2.7650x over previous
//
#include <hip/hip_runtime.h>

#define NTOK 32768
#define NE   2048
#define EDIM 128
#define NQ   4

#define TOKT 64
#define CHCODES 64               // codes per staged chunk (16 KB bf16)
#define NCHUNK (NE / CHCODES)    // 32
#define CAP 16
#define MARGIN 0.25f

typedef __attribute__((ext_vector_type(8))) short short8v;   // 8 bf16
typedef __attribute__((ext_vector_type(4))) float f32x4;

__device__ __forceinline__ unsigned short bf16rne(float x) {
    unsigned u = __float_as_uint(x);
    unsigned r = 0x7FFFu + ((u >> 16) & 1u);
    return (unsigned short)((u + r) >> 16);
}

__device__ __forceinline__ void gld16(const void* g, const void* l) {
    __builtin_amdgcn_global_load_lds(
        (const __attribute__((address_space(1))) unsigned int*)g,
        (__attribute__((address_space(3))) unsigned int*)l, 16, 0, 0);
}

// ---------------------------------------------------------------------------
// prep: per-code fp32 norms (sequential, same as rounds 1-8) + bf16 convert
// with dim-XOR swizzle (dim ^ ((code&7)<<3)) + zero loss accumulator.
// one thread per code row; grid = NQ*NE/256 = 32.
// ---------------------------------------------------------------------------
__global__ __launch_bounds__(256) void prep_kernel(
    const float* __restrict__ cb, unsigned short* __restrict__ cb16s,
    float* __restrict__ cnorm, float* __restrict__ loss_accum)
{
    const int row = blockIdx.x * 256 + threadIdx.x;   // 0..NQ*NE-1
    if (row == 0) *loss_accum = 0.0f;
    const float* src = cb + (size_t)row * EDIM;
    unsigned short* dst = cb16s + (size_t)row * EDIM;
    const int swz8 = (row & 7) << 3;                  // dim-index XOR key
    float s = 0.0f;
#pragma unroll
    for (int j = 0; j < EDIM / 4; ++j) {
        float4 v = ((const float4*)src)[j];
        s += v.x * v.x; s += v.y * v.y; s += v.z * v.z; s += v.w * v.w;
        ushort4 o;
        o.x = bf16rne(v.x); o.y = bf16rne(v.y);
        o.z = bf16rne(v.z); o.w = bf16rne(v.w);
        *(ushort4*)(dst + ((j * 4) ^ swz8)) = o;      // 4-group stays contiguous
    }
    cnorm[row] = s;
}

// ---------------------------------------------------------------------------
// One VQ level, MFMA 2-pass + fp32 refine. grid=512, 256 thr (4 waves),
// wave w owns tokens w*16..+15 x ALL codes. ~73.5 KB LDS -> 2 blocks/CU.
// ---------------------------------------------------------------------------
__global__ __launch_bounds__(256, 2) void vq_level_kernel(
    const float* __restrict__ rin,
    const float* __restrict__ cbF,        // fp32 codebook (refine + gather)
    const unsigned short* __restrict__ cbL, // bf16 swizzled codebook (level)
    const float* __restrict__ cnorm,      // [NE] fp32 (level)
    float* __restrict__ rout,
    float* __restrict__ xq,
    float* __restrict__ idx_out,
    float* __restrict__ loss_accum,
    int level, int first)
{
    __shared__ __align__(16) float Af[TOKT][132];              // 33792 B
    __shared__ __align__(16) unsigned short Bs[2][CHCODES * EDIM]; // 32768 B
    __shared__ float part[4 * 64];
    __shared__ float rns[TOKT];
    __shared__ int   cnt[TOKT];
    __shared__ int   lst[TOKT * CAP];
    __shared__ int   idx_s[TOKT];
    __shared__ float lsum[256];

    const int t    = threadIdx.x;
    const int tok0 = blockIdx.x * TOKT;
    const int l    = t & 63;
    const int w    = t >> 6;
    const int cl   = l & 15;          // MFMA col / A-row lane
    const int lg   = l >> 4;          // k-group
    if (t < TOKT) cnt[t] = 0;

    // ---- stage residual row-major + partial norms (round-8 association) ----
    {
        const int tok = t & 63;
        const int dg  = t >> 6;
        float s = 0.0f;
#pragma unroll
        for (int j = 0; j < 8; ++j) {
            const int d0 = dg * 32 + j * 4;
            float4 v = *(const float4*)(rin + (size_t)(tok0 + tok) * EDIM + d0);
            *(float4*)&Af[tok][d0] = v;
            s += v.x * v.x; s += v.y * v.y; s += v.z * v.z; s += v.w * v.w;
        }
        part[dg * 64 + tok] = s;
    }
    __syncthreads();
    if (t < TOKT)
        rns[t] = ((part[t] + part[64 + t]) + part[128 + t]) + part[192 + t];

    // ---- A fragments: lane = token w*16+cl, k = kt*32 + lg*8 + j ----
    const int arow = w * 16 + cl;
    short8v af0, af1, af2, af3;
#define LDA(AF, KT) { \
    float4 p0 = *(const float4*)&Af[arow][(KT) * 32 + lg * 8]; \
    float4 p1 = *(const float4*)&Af[arow][(KT) * 32 + lg * 8 + 4]; \
    AF[0] = (short)bf16rne(p0.x); AF[1] = (short)bf16rne(p0.y); \
    AF[2] = (short)bf16rne(p0.z); AF[3] = (short)bf16rne(p0.w); \
    AF[4] = (short)bf16rne(p1.x); AF[5] = (short)bf16rne(p1.y); \
    AF[6] = (short)bf16rne(p1.z); AF[7] = (short)bf16rne(p1.w); }
    LDA(af0, 0) LDA(af1, 1) LDA(af2, 2) LDA(af3, 3)
#undef LDA

    // B read addressing: inner byte (kt*64 + lg*16) ^ swzk within code row
    const int swzk = (cl & 7) << 4;
    const int inn0 = (0   + lg * 16) ^ swzk;
    const int inn1 = (64  + lg * 16) ^ swzk;
    const int inn2 = (128 + lg * 16) ^ swzk;
    const int inn3 = (192 + lg * 16) ^ swzk;

#define STAGE(DST, CH) { \
    const char* gs = (const char*)cbL + (size_t)(CH) * 16384 + t * 16; \
    char* ls = (char*)(DST) + (t & 192) * 16; \
    gld16(gs,         ls); \
    gld16(gs + 4096,  ls + 4096); \
    gld16(gs + 8192,  ls + 8192); \
    gld16(gs + 12288, ls + 12288); }

#define MFMA4(BUFC, CH, CT, TAIL) { \
    const char* bp = (const char*)&Bs[BUFC][0] + ((CT) * 16 + cl) * 256; \
    short8v b0 = *(const short8v*)(bp + inn0); \
    short8v b1 = *(const short8v*)(bp + inn1); \
    short8v b2 = *(const short8v*)(bp + inn2); \
    short8v b3 = *(const short8v*)(bp + inn3); \
    f32x4 acc = {0.f, 0.f, 0.f, 0.f}; \
    acc = __builtin_amdgcn_mfma_f32_16x16x32_bf16(af0, b0, acc, 0, 0, 0); \
    acc = __builtin_amdgcn_mfma_f32_16x16x32_bf16(af1, b1, acc, 0, 0, 0); \
    acc = __builtin_amdgcn_mfma_f32_16x16x32_bf16(af2, b2, acc, 0, 0, 0); \
    acc = __builtin_amdgcn_mfma_f32_16x16x32_bf16(af3, b3, acc, 0, 0, 0); \
    const int code = (CH) * 64 + (CT) * 16 + cl; \
    const float cn = cnorm[code]; \
    TAIL }

#define T_MIN \
    md0 = fminf(md0, (rn40 - 2.f * acc[0]) + cn); \
    md1 = fminf(md1, (rn41 - 2.f * acc[1]) + cn); \
    md2 = fminf(md2, (rn42 - 2.f * acc[2]) + cn); \
    md3 = fminf(md3, (rn43 - 2.f * acc[3]) + cn);

#define PUSH(R, TH) { float dd = (rn4##R - 2.f * acc[R]) + cn; \
    if (dd < TH) { int p = atomicAdd(&cnt[tokb + R], 1); \
                   if (p < CAP) lst[(tokb + R) * CAP + p] = code; } }
#define T_CAND PUSH(0, th0) PUSH(1, th1) PUSH(2, th2) PUSH(3, th3)

#define CH_P1(BUFC, CH) { \
    MFMA4(BUFC, CH, 0, T_MIN) MFMA4(BUFC, CH, 1, T_MIN) \
    MFMA4(BUFC, CH, 2, T_MIN) MFMA4(BUFC, CH, 3, T_MIN) }
#define CH_P2(BUFC, CH) { \
    MFMA4(BUFC, CH, 0, T_CAND) MFMA4(BUFC, CH, 1, T_CAND) \
    MFMA4(BUFC, CH, 2, T_CAND) MFMA4(BUFC, CH, 3, T_CAND) }

    // ---- PASS 1: per-token min of approx distance ----
    STAGE(&Bs[0][0], 0)
    __syncthreads();                       // chunk0 resident; rns visible

    const int tokb = w * 16 + lg * 4;      // C/D row map: row = lg*4 + reg
    const float rn40 = rns[tokb + 0], rn41 = rns[tokb + 1];
    const float rn42 = rns[tokb + 2], rn43 = rns[tokb + 3];

    float md0 = 3.402823466e38f, md1 = md0, md2 = md0, md3 = md0;

    for (int c2 = 0; c2 < NCHUNK / 2; ++c2) {
        const int c = c2 * 2;
        STAGE(&Bs[1][0], c + 1)
        CH_P1(0, c)
        __syncthreads();
        if (c + 2 < NCHUNK) STAGE(&Bs[0][0], c + 2)
        CH_P1(1, c + 1)
        __syncthreads();
    }

    // reduce min across the 16 code-lanes (same lg, same 4 tokens)
#pragma unroll
    for (int m = 1; m < 16; m <<= 1) {
        md0 = fminf(md0, __shfl_xor(md0, m, 64));
        md1 = fminf(md1, __shfl_xor(md1, m, 64));
        md2 = fminf(md2, __shfl_xor(md2, m, 64));
        md3 = fminf(md3, __shfl_xor(md3, m, 64));
    }
    const float th0 = md0 + MARGIN, th1 = md1 + MARGIN;
    const float th2 = md2 + MARGIN, th3 = md3 + MARGIN;

    // ---- PASS 2: collect candidates within MARGIN of the min ----
    STAGE(&Bs[0][0], 0)
    __syncthreads();
    for (int c2 = 0; c2 < NCHUNK / 2; ++c2) {
        const int c = c2 * 2;
        STAGE(&Bs[1][0], c + 1)
        CH_P2(0, c)
        __syncthreads();
        if (c + 2 < NCHUNK) STAGE(&Bs[0][0], c + 2)
        CH_P2(1, c + 1)
        __syncthreads();
    }

    // ---- refine: exact fp32 sequential distance over candidates ----
    if (t < TOKT) {
        const int n = min(cnt[t], CAP);
        const float rn_t = rns[t];
        float bd = 3.402823466e38f;
        int   bi = 0x7fffffff;
        for (int i = 0; i < n; ++i) {
            const int c = lst[t * CAP + i];
            const float* cr = cbF + (size_t)c * EDIM;
            float dot = 0.0f;
#pragma unroll 8
            for (int d = 0; d < EDIM; ++d)
                dot = fmaf(Af[t][d], cr[d], dot);    // same chain as rounds 1-8
            const float dd = (rn_t - 2.0f * dot) + cnorm[c];
            if (dd < bd || (dd == bd && c < bi)) { bd = dd; bi = c; }
        }
        idx_s[t] = bi;
        idx_out[(size_t)(tok0 + t) * NQ + level] = (float)bi;
    }
    __syncthreads();

    // ---- epilogue: gather + straight-through update + loss partial ----
    {
        const int tok = t >> 2;
        const int dq  = t & 3;
        const int gi  = idx_s[tok];
        const float* qrow = cbF + (size_t)gi * EDIM;
        float lp = 0.0f;
#pragma unroll
        for (int k = 0; k < 8; ++k) {
            const int d0 = k * 16 + dq * 4;
            const float4 q = *(const float4*)(qrow + d0);
            const float4 r = *(const float4*)&Af[tok][d0];
            float4 tq, qst, rnv;
            tq.x = q.x - r.x; tq.y = q.y - r.y; tq.z = q.z - r.z; tq.w = q.w - r.w;
            qst.x = r.x + tq.x; qst.y = r.y + tq.y;
            qst.z = r.z + tq.z; qst.w = r.w + tq.w;
            rnv.x = r.x - qst.x; rnv.y = r.y - qst.y;
            rnv.z = r.z - qst.z; rnv.w = r.w - qst.w;
            const size_t go = (size_t)(tok0 + tok) * EDIM + d0;
            *(float4*)(rout + go) = rnv;
            if (first) {
                *(float4*)(xq + go) = qst;
            } else {
                float4 o = *(const float4*)(xq + go);
                o.x += qst.x; o.y += qst.y; o.z += qst.z; o.w += qst.w;
                *(float4*)(xq + go) = o;
            }
            lp += tq.x * tq.x; lp += tq.y * tq.y;
            lp += tq.z * tq.z; lp += tq.w * tq.w;
        }
        lsum[t] = lp;
    }
    __syncthreads();
#pragma unroll
    for (int s2 = 128; s2 > 0; s2 >>= 1) {
        if (t < s2) lsum[t] += lsum[t + s2];
        __syncthreads();
    }
    if (t == 0) atomicAdd(loss_accum, lsum[0]);
}

// ---------------------------------------------------------------------------
__global__ void finalize_kernel(const float* __restrict__ loss_accum,
                                float* __restrict__ out_loss)
{
    *out_loss = *loss_accum * (1.25f / (4.0f * (float)NTOK * (float)EDIM));
}

extern "C" void kernel_launch(void* const* d_in, const int* in_sizes, int n_in,
                              void* d_out, int out_size, void* d_ws, size_t ws_size,
                              hipStream_t stream)
{
    const float* x  = (const float*)d_in[0];
    const float* cb = (const float*)d_in[1];

    float* out      = (float*)d_out;
    float* xq       = out;
    float* out_loss = out + (size_t)NTOK * EDIM;
    float* idx_out  = out + (size_t)NTOK * EDIM + 1;

    float* ws             = (float*)d_ws;
    float* cnorm          = ws;                            // NQ*NE
    float* loss_accum     = ws + 8192;
    unsigned short* cb16s = (unsigned short*)(ws + 8448);  // NQ*NE*EDIM bf16
    float* r0             = ws + 8448 + (size_t)NQ * NE * EDIM / 2;

    prep_kernel<<<(NQ * NE) / 256, 256, 0, stream>>>(cb, cb16s, cnorm, loss_accum);

    for (int l = 0; l < NQ; ++l) {
        const float* rin = (l == 0) ? x : r0;
        vq_level_kernel<<<NTOK / TOKT, 256, 0, stream>>>(
            rin, cb + (size_t)l * NE * EDIM,
            cb16s + (size_t)l * NE * EDIM,
            cnorm + (size_t)l * NE,
            r0, xq, idx_out, loss_accum, l, (l == 0) ? 1 : 0);
    }
    finalize_kernel<<<1, 1, 0, stream>>>(loss_accum, out_loss);
}